// Round 11
// baseline (466.974 us; speedup 1.0000x reference)
//
#include <hip/hip_runtime.h>

// Problem: B=256, N=1000, D=128, H=8, dk=16.
// R9 (3rd submit; two GPUAcquisitionTimeouts on this source, never executed):
// abandon cooperative pair-split (8 rounds of occupancy cliffs). Structure:
// 5 stream-ordered kernels, cross-half reductions pass through d_ws at kernel
// boundaries (dispatch release/acquire makes writes visible — no spin sync,
// no coop launch, no atomics).
//   K1 mean-partials (512x512): muP[blk][128] partial sums over 500 rows.
//   K2 attention    (512x512): mu,q,qkp then NO-MAX softmax over its half:
//                              U=Sum exp(compat)*E, l=Sum exp(compat).
//   K3 glimpse      (256x1024): Ebar=(U0+U1)/(l0+l1) -> heads -> gl -> gp.
//   K4 logits       (512x512): z=10*tanh(E.gp/sqrt128), masked; out=z;
//                              s=Sum exp(z-10) partial.
//   K5 normalize    (512x512): out -= 10 + log(s0+s1).
// No-max softmax is numerically safe: compat ~ N(0,1) by construction
// (unit-var E dot 128-dim qkp with var 1/128) -> max ~5 sigma, exp() cannot
// overflow fp32; logits tanh-clipped to [-10,10] so LSE=10+log(sum) is exact.
// This removes the per-tile max machinery (5->3 barriers/tile, no serial
// t<8 sections) and makes cross-half combines plain additions.
// 512-thr blocks + __launch_bounds__(512,4) guarantee >=2 blocks/CU
// (16 waves) so barrier stalls overlap across co-resident blocks.

#define NEG (-1e9f)

// ---------------- K1: partial mean sums over this half's 500 rows ----------
__global__ __launch_bounds__(512, 4) void k1_mean(
    const float* __restrict__ E, float* __restrict__ muP)
{
    const int bid = blockIdx.x;
    const int b = bid & 255, half = bid >> 8;
    const int blk = b * 2 + half;
    const int t = threadIdx.x;
    const int r0g = half * 500;
    __shared__ float4 sc[512];
    const float4* E4 = (const float4*)(E + (size_t)b * 128000);
    const int cm = t & 31, sm = t >> 5;       // 16 slices x 32 cols
    float4 acc = make_float4(0.f, 0.f, 0.f, 0.f);
    for (int r = sm; r < 500; r += 16) {
        const float4 v = E4[(r0g + r) * 32 + cm];
        acc.x += v.x; acc.y += v.y; acc.z += v.z; acc.w += v.w;
    }
    sc[t] = acc;
    __syncthreads();
    if (t < 32) {
        float4 a = sc[t];
        #pragma unroll
        for (int s = 1; s < 16; ++s) {
            const float4 v = sc[s * 32 + t];
            a.x += v.x; a.y += v.y; a.z += v.z; a.w += v.w;
        }
        ((float4*)(muP + (size_t)blk * 128))[t] = a;   // partial SUM
    }
}

// ---------------- K2: q/qkp + no-max attention partials --------------------
__global__ __launch_bounds__(512, 4) void k2_attn(
    const float* __restrict__ E, const float* __restrict__ Wn,
    const float* __restrict__ Wf, const float* __restrict__ Ws,
    const int* __restrict__ fi, const int* __restrict__ li,
    const int* __restrict__ maskI, const unsigned char* __restrict__ maskB,
    const float* __restrict__ muP, float* __restrict__ Uw,
    float* __restrict__ lw)
{
    const int bid = blockIdx.x;
    const int b = bid & 255, half = bid >> 8;
    const int blk = b * 2 + half;
    const int i0 = b * 2, i1 = i0 + 1;
    const int t = threadIdx.x;
    const int r0g = half * 500;

    __shared__ float4 Et4[2048];     // 32 KB: 64-row E tile / slice reduce
    __shared__ float4 qk4[256];      // qkp, float4-slot swizzle s^(s>>2)
    __shared__ float4 pt4[128];      // p [row][h], 512 floats
    __shared__ float4 mu4[32], e14[32], e24[32];
    __shared__ float q[128];
    __shared__ float qred[4][128];
    __shared__ float ct[64 * 9];     // compat [row][h] pad 9
    __shared__ float redh[72];
    __shared__ int flagS;

    float* const mu  = (float*)mu4;
    float* const e1  = (float*)e14;
    float* const e2  = (float*)e24;
    float* const pt  = (float*)pt4;
    float* const qkf = (float*)qk4;
    float* const Etf = (float*)Et4;

    const float4* E4 = (const float4*)(E + (size_t)b * 128000);

    if (t == 0) flagS = 0;
    // mask-format probe: int32 upload => upper 3 bytes of every word zero.
    const uint4 dv = ((const uint4*)maskI)[t];          // first 8 KB
    const unsigned det = (dv.x | dv.y | dv.z | dv.w) & 0xFFFFFF00u;

    if (t < 128) {
        mu[t] = (muP[(size_t)i0 * 128 + t] + muP[(size_t)i1 * 128 + t])
                * (1.0f / 1000.0f);
    } else if (t < 160) {
        e14[t - 128] = E4[fi[b] * 32 + (t - 128)];
    } else if (t < 192) {
        e24[t - 160] = E4[li[b] * 32 + (t - 160)];
    }
    __syncthreads();
    if (det) atomicOr(&flagS, 1);

    // q = mu@Wf + e1@Ws[0:128] + e2@Ws[128:256], 4-way k-split
    {
        const int part = t >> 7, d = t & 127;
        float acc = 0.f;
        const int k0 = part * 96;
        for (int k = k0; k < k0 + 96; ++k) {
            const float s = (k < 128) ? mu[k] : (k < 256 ? e1[k - 128] : e2[k - 256]);
            const float w = (k < 128) ? Wf[k * 128 + d] : Ws[(k - 128) * 128 + d];
            acc += s * w;
        }
        qred[part][d] = acc;
    }
    __syncthreads();
    if (t < 128) q[t] = qred[0][t] + qred[1][t] + qred[2][t] + qred[3][t];
    __syncthreads();
    // qkp[h][c] -> qk4 (LDS only), 4 c-groups
    {
        const int j = t & 127, cg = t >> 7;
        const float qj = q[j];
        for (int c0 = 0; c0 < 128; c0 += 4) {
            const int c = c0 + cg;
            float v = Wn[c * 384 + j] * qj;
            v += __shfl_down(v, 8, 16);
            v += __shfl_down(v, 4, 16);
            v += __shfl_down(v, 2, 16);
            v += __shfl_down(v, 1, 16);
            if ((j & 15) == 0) {
                const int h = j >> 4, s = c >> 2;
                qkf[h * 128 + (s ^ (s >> 2)) * 4 + (c & 3)] = v * 0.25f;
            }
        }
    }
    __syncthreads();
    const bool useB = (flagS != 0);

    // no-max online accumulation: 8 tiles x 64 rows
    float eacc[8];
    #pragma unroll
    for (int h = 0; h < 8; ++h) eacc[h] = 0.f;
    float lacc = 0.f;
    const int rr = t >> 3, qq = t & 7;     // stage: 64 rows x 8 lanes
    const int esl = t >> 7, ec = t & 127;  // accum: 4 slices x 128 cols

    for (int tile = 0; tile < 8; ++tile) {
        const int lr = tile * 64 + rr;
        const bool valid = (lr < 500);
        {
            float4 v[4];
            if (valid) {
                #pragma unroll
                for (int i = 0; i < 4; ++i) v[i] = E4[(r0g + lr) * 32 + qq * 4 + i];
            } else {
                #pragma unroll
                for (int i = 0; i < 4; ++i) v[i] = make_float4(0.f, 0.f, 0.f, 0.f);
            }
            float pch[8];
            #pragma unroll
            for (int h = 0; h < 8; ++h) pch[h] = 0.f;
            #pragma unroll
            for (int i = 0; i < 4; ++i) {
                const int grp = qq * 4 + i;
                Et4[rr * 32 + grp] = v[i];        // linear row-major tile
                const int sg = grp ^ (grp >> 2);
                #pragma unroll
                for (int h = 0; h < 8; ++h) {
                    const float4 w = qk4[h * 32 + sg];
                    pch[h] += v[i].x * w.x + v[i].y * w.y + v[i].z * w.z + v[i].w * w.w;
                }
            }
            #pragma unroll
            for (int m = 1; m <= 4; m <<= 1) {
                #pragma unroll
                for (int h = 0; h < 8; ++h) pch[h] += __shfl_xor(pch[h], m, 8);
            }
            bool msk = !valid;
            if (valid) msk = useB ? (maskB[b * 1000 + r0g + lr] != 0)
                                  : (maskI[b * 1000 + r0g + lr] != 0);
            ct[rr * 9 + qq] = msk ? NEG : pch[qq];
        }
        __syncthreads();
        // p = exp(compat), fixed shift 0 (safe: compat ~ N(0,1)); exp(NEG)=0
        pt[(t >> 3) * 8 + (t & 7)] = __expf(ct[(t >> 3) * 9 + (t & 7)]);
        __syncthreads();
        {
            #pragma unroll
            for (int j = 0; j < 16; ++j) {
                const int r = esl * 16 + j;
                const float ev = Etf[r * 128 + ec];   // stride-1: 2-way, free
                const float4 p0 = pt4[r * 2];         // broadcast
                const float4 p1 = pt4[r * 2 + 1];
                eacc[0] += p0.x * ev; eacc[1] += p0.y * ev;
                eacc[2] += p0.z * ev; eacc[3] += p0.w * ev;
                eacc[4] += p1.x * ev; eacc[5] += p1.y * ev;
                eacc[6] += p1.z * ev; eacc[7] += p1.w * ev;
            }
            if (t < 64) {
                const int h = t & 7, part = t >> 3;
                #pragma unroll
                for (int r = 0; r < 8; ++r) lacc += pt[(part * 8 + r) * 8 + h];
            }
        }
        __syncthreads();   // before next tile overwrites Et4/ct/pt
    }

    // slice-reduce U (4 slices) and l (8 parts), publish to workspace
    #pragma unroll
    for (int h = 0; h < 8; ++h) Etf[esl * 1024 + h * 128 + ec] = eacc[h];
    if (t < 64) redh[(t >> 3) * 9 + (t & 7)] = lacc;
    __syncthreads();
    #pragma unroll
    for (int e = 0; e < 2; ++e) {
        const int idx = t + e * 512;
        Uw[(size_t)blk * 1024 + idx] =
            Etf[idx] + Etf[1024 + idx] + Etf[2048 + idx] + Etf[3072 + idx];
    }
    if (t < 8) {
        float s = 0.f;
        #pragma unroll
        for (int p = 0; p < 8; ++p) s += redh[p * 9 + t];
        lw[blk * 8 + t] = s;
    }
}

// ---------------- K3: combine halves -> Ebar -> heads -> glimpse -> gp -----
__global__ __launch_bounds__(1024) void k3_glimpse(
    const float* __restrict__ Wn, const float* __restrict__ Wo,
    const float* __restrict__ Uw, const float* __restrict__ lw,
    float* __restrict__ gpw)
{
    const int b = blockIdx.x;
    const int t = threadIdx.x;
    const int i0 = b * 2, i1 = i0 + 1;
    __shared__ float EbarF[1024];
    __shared__ float linv[8];
    __shared__ float heads[128], gl[128];
    __shared__ float qred[8][128];
    if (t < 8) linv[t] = 1.0f / (lw[i0 * 8 + t] + lw[i1 * 8 + t]);
    __syncthreads();
    EbarF[t] = (Uw[(size_t)i0 * 1024 + t] + Uw[(size_t)i1 * 1024 + t]) * linv[t >> 7];
    __syncthreads();
    {
        const int part = t >> 7, d = t & 127, h = d >> 4;
        float acc = 0.f;
        const int c0 = part * 16;
        for (int c = c0; c < c0 + 16; ++c) acc += EbarF[h * 128 + c] * Wn[c * 384 + 128 + d];
        qred[part][d] = acc;
    }
    __syncthreads();
    if (t < 128) {
        float a = 0.f;
        #pragma unroll
        for (int p = 0; p < 8; ++p) a += qred[p][t];
        heads[t] = a;
    }
    __syncthreads();
    {
        const int part = t >> 7, d = t & 127;
        float acc = 0.f;
        const int j0 = part * 16;
        for (int j = j0; j < j0 + 16; ++j) acc += heads[j] * Wo[j * 128 + d];
        qred[part][d] = acc;
    }
    __syncthreads();
    if (t < 128) {
        float a = 0.f;
        #pragma unroll
        for (int p = 0; p < 8; ++p) a += qred[p][t];
        gl[t] = a;
    }
    __syncthreads();
    {
        const int part = t >> 7, c = t & 127;
        float acc = 0.f;
        const int d0 = part * 16;
        for (int d = d0; d < d0 + 16; ++d) acc += Wn[c * 384 + 256 + d] * gl[d];
        qred[part][c] = acc;
    }
    __syncthreads();
    if (t < 128) {
        float a = 0.f;
        #pragma unroll
        for (int p = 0; p < 8; ++p) a += qred[p][t];
        gpw[(size_t)b * 128 + t] = a * 0.08838834764831845f;   // 1/sqrt(128)
    }
}

// ---------------- K4: logits + masked z -> out, partial exp-sum ------------
__global__ __launch_bounds__(512, 4) void k4_logits(
    const float* __restrict__ E,
    const int* __restrict__ maskI, const unsigned char* __restrict__ maskB,
    const float* __restrict__ gpw, float* __restrict__ out,
    float* __restrict__ sw)
{
    const int bid = blockIdx.x;
    const int b = bid & 255, half = bid >> 8;
    const int blk = b * 2 + half;
    const int t = threadIdx.x;
    const int r0g = half * 500;
    __shared__ float4 gp4[32];
    __shared__ float ct[128 * 5];
    __shared__ float red[8];
    __shared__ int flagS;
    const float4* E4 = (const float4*)(E + (size_t)b * 128000);
    if (t == 0) flagS = 0;
    const uint4 dv = ((const uint4*)maskI)[t];
    const unsigned det = (dv.x | dv.y | dv.z | dv.w) & 0xFFFFFF00u;
    if (t < 32) gp4[t] = ((const float4*)(gpw + (size_t)b * 128))[t];
    __syncthreads();
    if (det) atomicOr(&flagS, 1);

    float sacc = 0.f;
    const int row = t >> 2, sub = t & 3;   // 128 rows x 4 lanes (8 f4 each)
    for (int tile = 0; tile < 4; ++tile) {
        const int lr = tile * 128 + row;
        float acc = 0.f;
        if (lr < 500) {
            const int g = r0g + lr;
            #pragma unroll
            for (int i = 0; i < 8; ++i) {
                const float4 v = E4[g * 32 + sub * 8 + i];
                const float4 w = gp4[sub * 8 + i];
                acc += v.x * w.x + v.y * w.y + v.z * w.z + v.w * w.w;
            }
        }
        ct[row * 5 + sub] = acc;
        __syncthreads();
        if (t < 128) {
            const int lr2 = tile * 128 + t;
            if (lr2 < 500) {
                const float s = ct[t * 5] + ct[t * 5 + 1] + ct[t * 5 + 2] + ct[t * 5 + 3];
                float zz = 10.0f * tanhf(s);
                const int g2 = r0g + lr2;
                const bool m = (flagS != 0) ? (maskB[b * 1000 + g2] != 0)
                                            : (maskI[b * 1000 + g2] != 0);
                if (m) zz = NEG;
                out[(size_t)b * 1000 + g2] = zz;
                sacc += __expf(zz - 10.0f);   // z<=10 -> no overflow; exp(NEG)=0
            }
        }
        __syncthreads();
    }
    // reduce sacc (nonzero only in waves 0-1)
    float sv = sacc;
    #pragma unroll
    for (int off = 32; off > 0; off >>= 1) sv += __shfl_down(sv, off, 64);
    if ((t & 63) == 0) red[t >> 6] = sv;
    __syncthreads();
    if (t == 0) {
        float s = 0.f;
        #pragma unroll
        for (int i = 0; i < 8; ++i) s += red[i];
        sw[blk] = s;
    }
}

// ---------------- K5: out -= LSE (combine half exp-sums) -------------------
__global__ __launch_bounds__(512, 4) void k5_norm(
    const float* __restrict__ sw, float* __restrict__ out)
{
    const int bid = blockIdx.x;
    const int b = bid & 255, half = bid >> 8;
    const int t = threadIdx.x;
    const int r0g = half * 500;
    const float s = sw[b * 2] + sw[b * 2 + 1];
    const float lse = 10.0f + __logf(s);
    if (t < 500) out[(size_t)b * 1000 + r0g + t] -= lse;
}

// ---------------------------------------------------------------------------
extern "C" void kernel_launch(void* const* d_in, const int* in_sizes, int n_in,
                              void* d_out, int out_size, void* d_ws, size_t ws_size,
                              hipStream_t stream) {
    const float* E  = (const float*)d_in[0];
    const float* Wn = (const float*)d_in[1];
    const float* Wf = (const float*)d_in[2];
    const float* Ws = (const float*)d_in[3];
    const float* Wo = (const float*)d_in[4];
    const int*   fi = (const int*)d_in[5];
    const int*   li = (const int*)d_in[6];
    const int*   maskI = (const int*)d_in[7];
    const unsigned char* maskB = (const unsigned char*)d_in[7];
    float* out = (float*)d_out;
    float* ws  = (float*)d_ws;

    // workspace layout (floats): total ~2.39 MB
    float* muP = ws;                          // [512][128]
    float* Uw  = ws + 512 * 128;              // [512][1024]
    float* lw  = Uw + (size_t)512 * 1024;     // [512][8]
    float* gpw = lw + 512 * 8;                // [256][128]
    float* sw  = gpw + 256 * 128;             // [512]

    k1_mean   <<<dim3(512), dim3(512),  0, stream>>>(E, muP);
    k2_attn   <<<dim3(512), dim3(512),  0, stream>>>(E, Wn, Wf, Ws, fi, li,
                                                     maskI, maskB, muP, Uw, lw);
    k3_glimpse<<<dim3(256), dim3(1024), 0, stream>>>(Wn, Wo, Uw, lw, gpw);
    k4_logits <<<dim3(512), dim3(512),  0, stream>>>(E, maskI, maskB, gpw, out, sw);
    k5_norm   <<<dim3(512), dim3(512),  0, stream>>>(sw, out);
}

// Round 12
// 348.067 us; speedup vs baseline: 1.3416x; 1.3416x over previous
//
#include <hip/hip_runtime.h>

// Problem: B=256, N=1000, D=128, H=8, dk=16.
// R10: R9 ran — 467us total, k2=263us with FETCH 429MB / WRITE 437MB =
// ~430MB scratch spill round-trip. VGPR_Count=64 = 256/4: third data point
// for the rule "VGPR cap = 256 / min_waves_per_EU, independent of block
// size" ((1024,8)->32, (512,4)->64). k2's live set (~60-100 regs) spilled
// every tile iteration. FIX: k2,k4 -> __launch_bounds__(512,2) (cap 128;
// usage <=128 still gives 4 waves/SIMD = 2 blocks/CU by the measured
// occupancy steps at VGPR 64/128/256). k1,k5 keep (512,4) (fit in 64).
// Everything else identical to R9 for clean attribution.
//   K1 mean-partials; K2 no-max attention; K3 glimpse; K4 logits; K5 norm.
// No-max softmax safety: compat ~ N(0,1) by construction -> exp() safe at
// shift 0; logits tanh-clipped -> LSE = 10 + log(sum exp(z-10)) exact.

#define NEG (-1e9f)

// ---------------- K1: partial mean sums over this half's 500 rows ----------
__global__ __launch_bounds__(512, 4) void k1_mean(
    const float* __restrict__ E, float* __restrict__ muP)
{
    const int bid = blockIdx.x;
    const int b = bid & 255, half = bid >> 8;
    const int blk = b * 2 + half;
    const int t = threadIdx.x;
    const int r0g = half * 500;
    __shared__ float4 sc[512];
    const float4* E4 = (const float4*)(E + (size_t)b * 128000);
    const int cm = t & 31, sm = t >> 5;       // 16 slices x 32 cols
    float4 acc = make_float4(0.f, 0.f, 0.f, 0.f);
    for (int r = sm; r < 500; r += 16) {
        const float4 v = E4[(r0g + r) * 32 + cm];
        acc.x += v.x; acc.y += v.y; acc.z += v.z; acc.w += v.w;
    }
    sc[t] = acc;
    __syncthreads();
    if (t < 32) {
        float4 a = sc[t];
        #pragma unroll
        for (int s = 1; s < 16; ++s) {
            const float4 v = sc[s * 32 + t];
            a.x += v.x; a.y += v.y; a.z += v.z; a.w += v.w;
        }
        ((float4*)(muP + (size_t)blk * 128))[t] = a;   // partial SUM
    }
}

// ---------------- K2: q/qkp + no-max attention partials --------------------
__global__ __launch_bounds__(512, 2) void k2_attn(
    const float* __restrict__ E, const float* __restrict__ Wn,
    const float* __restrict__ Wf, const float* __restrict__ Ws,
    const int* __restrict__ fi, const int* __restrict__ li,
    const int* __restrict__ maskI, const unsigned char* __restrict__ maskB,
    const float* __restrict__ muP, float* __restrict__ Uw,
    float* __restrict__ lw)
{
    const int bid = blockIdx.x;
    const int b = bid & 255, half = bid >> 8;
    const int blk = b * 2 + half;
    const int i0 = b * 2, i1 = i0 + 1;
    const int t = threadIdx.x;
    const int r0g = half * 500;

    __shared__ float4 Et4[2048];     // 32 KB: 64-row E tile / slice reduce
    __shared__ float4 qk4[256];      // qkp, float4-slot swizzle s^(s>>2)
    __shared__ float4 pt4[128];      // p [row][h], 512 floats
    __shared__ float4 mu4[32], e14[32], e24[32];
    __shared__ float q[128];
    __shared__ float qred[4][128];
    __shared__ float ct[64 * 9];     // compat [row][h] pad 9
    __shared__ float redh[72];
    __shared__ int flagS;

    float* const mu  = (float*)mu4;
    float* const e1  = (float*)e14;
    float* const e2  = (float*)e24;
    float* const pt  = (float*)pt4;
    float* const qkf = (float*)qk4;
    float* const Etf = (float*)Et4;

    const float4* E4 = (const float4*)(E + (size_t)b * 128000);

    if (t == 0) flagS = 0;
    // mask-format probe: int32 upload => upper 3 bytes of every word zero.
    const uint4 dv = ((const uint4*)maskI)[t];          // first 8 KB
    const unsigned det = (dv.x | dv.y | dv.z | dv.w) & 0xFFFFFF00u;

    if (t < 128) {
        mu[t] = (muP[(size_t)i0 * 128 + t] + muP[(size_t)i1 * 128 + t])
                * (1.0f / 1000.0f);
    } else if (t < 160) {
        e14[t - 128] = E4[fi[b] * 32 + (t - 128)];
    } else if (t < 192) {
        e24[t - 160] = E4[li[b] * 32 + (t - 160)];
    }
    __syncthreads();
    if (det) atomicOr(&flagS, 1);

    // q = mu@Wf + e1@Ws[0:128] + e2@Ws[128:256], 4-way k-split
    {
        const int part = t >> 7, d = t & 127;
        float acc = 0.f;
        const int k0 = part * 96;
        for (int k = k0; k < k0 + 96; ++k) {
            const float s = (k < 128) ? mu[k] : (k < 256 ? e1[k - 128] : e2[k - 256]);
            const float w = (k < 128) ? Wf[k * 128 + d] : Ws[(k - 128) * 128 + d];
            acc += s * w;
        }
        qred[part][d] = acc;
    }
    __syncthreads();
    if (t < 128) q[t] = qred[0][t] + qred[1][t] + qred[2][t] + qred[3][t];
    __syncthreads();
    // qkp[h][c] -> qk4 (LDS only), 4 c-groups
    {
        const int j = t & 127, cg = t >> 7;
        const float qj = q[j];
        for (int c0 = 0; c0 < 128; c0 += 4) {
            const int c = c0 + cg;
            float v = Wn[c * 384 + j] * qj;
            v += __shfl_down(v, 8, 16);
            v += __shfl_down(v, 4, 16);
            v += __shfl_down(v, 2, 16);
            v += __shfl_down(v, 1, 16);
            if ((j & 15) == 0) {
                const int h = j >> 4, s = c >> 2;
                qkf[h * 128 + (s ^ (s >> 2)) * 4 + (c & 3)] = v * 0.25f;
            }
        }
    }
    __syncthreads();
    const bool useB = (flagS != 0);

    // no-max online accumulation: 8 tiles x 64 rows
    float eacc[8];
    #pragma unroll
    for (int h = 0; h < 8; ++h) eacc[h] = 0.f;
    float lacc = 0.f;
    const int rr = t >> 3, qq = t & 7;     // stage: 64 rows x 8 lanes
    const int esl = t >> 7, ec = t & 127;  // accum: 4 slices x 128 cols

    for (int tile = 0; tile < 8; ++tile) {
        const int lr = tile * 64 + rr;
        const bool valid = (lr < 500);
        {
            float4 v[4];
            if (valid) {
                #pragma unroll
                for (int i = 0; i < 4; ++i) v[i] = E4[(r0g + lr) * 32 + qq * 4 + i];
            } else {
                #pragma unroll
                for (int i = 0; i < 4; ++i) v[i] = make_float4(0.f, 0.f, 0.f, 0.f);
            }
            float pch[8];
            #pragma unroll
            for (int h = 0; h < 8; ++h) pch[h] = 0.f;
            #pragma unroll
            for (int i = 0; i < 4; ++i) {
                const int grp = qq * 4 + i;
                Et4[rr * 32 + grp] = v[i];        // linear row-major tile
                const int sg = grp ^ (grp >> 2);
                #pragma unroll
                for (int h = 0; h < 8; ++h) {
                    const float4 w = qk4[h * 32 + sg];
                    pch[h] += v[i].x * w.x + v[i].y * w.y + v[i].z * w.z + v[i].w * w.w;
                }
            }
            #pragma unroll
            for (int m = 1; m <= 4; m <<= 1) {
                #pragma unroll
                for (int h = 0; h < 8; ++h) pch[h] += __shfl_xor(pch[h], m, 8);
            }
            bool msk = !valid;
            if (valid) msk = useB ? (maskB[b * 1000 + r0g + lr] != 0)
                                  : (maskI[b * 1000 + r0g + lr] != 0);
            ct[rr * 9 + qq] = msk ? NEG : pch[qq];
        }
        __syncthreads();
        // p = exp(compat), fixed shift 0 (safe: compat ~ N(0,1)); exp(NEG)=0
        pt[(t >> 3) * 8 + (t & 7)] = __expf(ct[(t >> 3) * 9 + (t & 7)]);
        __syncthreads();
        {
            #pragma unroll
            for (int j = 0; j < 16; ++j) {
                const int r = esl * 16 + j;
                const float ev = Etf[r * 128 + ec];   // stride-1: 2-way, free
                const float4 p0 = pt4[r * 2];         // broadcast
                const float4 p1 = pt4[r * 2 + 1];
                eacc[0] += p0.x * ev; eacc[1] += p0.y * ev;
                eacc[2] += p0.z * ev; eacc[3] += p0.w * ev;
                eacc[4] += p1.x * ev; eacc[5] += p1.y * ev;
                eacc[6] += p1.z * ev; eacc[7] += p1.w * ev;
            }
            if (t < 64) {
                const int h = t & 7, part = t >> 3;
                #pragma unroll
                for (int r = 0; r < 8; ++r) lacc += pt[(part * 8 + r) * 8 + h];
            }
        }
        __syncthreads();   // before next tile overwrites Et4/ct/pt
    }

    // slice-reduce U (4 slices) and l (8 parts), publish to workspace
    #pragma unroll
    for (int h = 0; h < 8; ++h) Etf[esl * 1024 + h * 128 + ec] = eacc[h];
    if (t < 64) redh[(t >> 3) * 9 + (t & 7)] = lacc;
    __syncthreads();
    #pragma unroll
    for (int e = 0; e < 2; ++e) {
        const int idx = t + e * 512;
        Uw[(size_t)blk * 1024 + idx] =
            Etf[idx] + Etf[1024 + idx] + Etf[2048 + idx] + Etf[3072 + idx];
    }
    if (t < 8) {
        float s = 0.f;
        #pragma unroll
        for (int p = 0; p < 8; ++p) s += redh[p * 9 + t];
        lw[blk * 8 + t] = s;
    }
}

// ---------------- K3: combine halves -> Ebar -> heads -> glimpse -> gp -----
__global__ __launch_bounds__(1024) void k3_glimpse(
    const float* __restrict__ Wn, const float* __restrict__ Wo,
    const float* __restrict__ Uw, const float* __restrict__ lw,
    float* __restrict__ gpw)
{
    const int b = blockIdx.x;
    const int t = threadIdx.x;
    const int i0 = b * 2, i1 = i0 + 1;
    __shared__ float EbarF[1024];
    __shared__ float linv[8];
    __shared__ float heads[128], gl[128];
    __shared__ float qred[8][128];
    if (t < 8) linv[t] = 1.0f / (lw[i0 * 8 + t] + lw[i1 * 8 + t]);
    __syncthreads();
    EbarF[t] = (Uw[(size_t)i0 * 1024 + t] + Uw[(size_t)i1 * 1024 + t]) * linv[t >> 7];
    __syncthreads();
    {
        const int part = t >> 7, d = t & 127, h = d >> 4;
        float acc = 0.f;
        const int c0 = part * 16;
        for (int c = c0; c < c0 + 16; ++c) acc += EbarF[h * 128 + c] * Wn[c * 384 + 128 + d];
        qred[part][d] = acc;
    }
    __syncthreads();
    if (t < 128) {
        float a = 0.f;
        #pragma unroll
        for (int p = 0; p < 8; ++p) a += qred[p][t];
        heads[t] = a;
    }
    __syncthreads();
    {
        const int part = t >> 7, d = t & 127;
        float acc = 0.f;
        const int j0 = part * 16;
        for (int j = j0; j < j0 + 16; ++j) acc += heads[j] * Wo[j * 128 + d];
        qred[part][d] = acc;
    }
    __syncthreads();
    if (t < 128) {
        float a = 0.f;
        #pragma unroll
        for (int p = 0; p < 8; ++p) a += qred[p][t];
        gl[t] = a;
    }
    __syncthreads();
    {
        const int part = t >> 7, c = t & 127;
        float acc = 0.f;
        const int d0 = part * 16;
        for (int d = d0; d < d0 + 16; ++d) acc += Wn[c * 384 + 256 + d] * gl[d];
        qred[part][c] = acc;
    }
    __syncthreads();
    if (t < 128) {
        float a = 0.f;
        #pragma unroll
        for (int p = 0; p < 8; ++p) a += qred[p][t];
        gpw[(size_t)b * 128 + t] = a * 0.08838834764831845f;   // 1/sqrt(128)
    }
}

// ---------------- K4: logits + masked z -> out, partial exp-sum ------------
__global__ __launch_bounds__(512, 2) void k4_logits(
    const float* __restrict__ E,
    const int* __restrict__ maskI, const unsigned char* __restrict__ maskB,
    const float* __restrict__ gpw, float* __restrict__ out,
    float* __restrict__ sw)
{
    const int bid = blockIdx.x;
    const int b = bid & 255, half = bid >> 8;
    const int blk = b * 2 + half;
    const int t = threadIdx.x;
    const int r0g = half * 500;
    __shared__ float4 gp4[32];
    __shared__ float ct[128 * 5];
    __shared__ float red[8];
    __shared__ int flagS;
    const float4* E4 = (const float4*)(E + (size_t)b * 128000);
    if (t == 0) flagS = 0;
    const uint4 dv = ((const uint4*)maskI)[t];
    const unsigned det = (dv.x | dv.y | dv.z | dv.w) & 0xFFFFFF00u;
    if (t < 32) gp4[t] = ((const float4*)(gpw + (size_t)b * 128))[t];
    __syncthreads();
    if (det) atomicOr(&flagS, 1);

    float sacc = 0.f;
    const int row = t >> 2, sub = t & 3;   // 128 rows x 4 lanes (8 f4 each)
    for (int tile = 0; tile < 4; ++tile) {
        const int lr = tile * 128 + row;
        float acc = 0.f;
        if (lr < 500) {
            const int g = r0g + lr;
            #pragma unroll
            for (int i = 0; i < 8; ++i) {
                const float4 v = E4[g * 32 + sub * 8 + i];
                const float4 w = gp4[sub * 8 + i];
                acc += v.x * w.x + v.y * w.y + v.z * w.z + v.w * w.w;
            }
        }
        ct[row * 5 + sub] = acc;
        __syncthreads();
        if (t < 128) {
            const int lr2 = tile * 128 + t;
            if (lr2 < 500) {
                const float s = ct[t * 5] + ct[t * 5 + 1] + ct[t * 5 + 2] + ct[t * 5 + 3];
                float zz = 10.0f * tanhf(s);
                const int g2 = r0g + lr2;
                const bool m = (flagS != 0) ? (maskB[b * 1000 + g2] != 0)
                                            : (maskI[b * 1000 + g2] != 0);
                if (m) zz = NEG;
                out[(size_t)b * 1000 + g2] = zz;
                sacc += __expf(zz - 10.0f);   // z<=10 -> no overflow; exp(NEG)=0
            }
        }
        __syncthreads();
    }
    // reduce sacc (nonzero only in waves 0-1)
    float sv = sacc;
    #pragma unroll
    for (int off = 32; off > 0; off >>= 1) sv += __shfl_down(sv, off, 64);
    if ((t & 63) == 0) red[t >> 6] = sv;
    __syncthreads();
    if (t == 0) {
        float s = 0.f;
        #pragma unroll
        for (int i = 0; i < 8; ++i) s += red[i];
        sw[blk] = s;
    }
}

// ---------------- K5: out -= LSE (combine half exp-sums) -------------------
__global__ __launch_bounds__(512, 4) void k5_norm(
    const float* __restrict__ sw, float* __restrict__ out)
{
    const int bid = blockIdx.x;
    const int b = bid & 255, half = bid >> 8;
    const int t = threadIdx.x;
    const int r0g = half * 500;
    const float s = sw[b * 2] + sw[b * 2 + 1];
    const float lse = 10.0f + __logf(s);
    if (t < 500) out[(size_t)b * 1000 + r0g + t] -= lse;
}

// ---------------------------------------------------------------------------
extern "C" void kernel_launch(void* const* d_in, const int* in_sizes, int n_in,
                              void* d_out, int out_size, void* d_ws, size_t ws_size,
                              hipStream_t stream) {
    const float* E  = (const float*)d_in[0];
    const float* Wn = (const float*)d_in[1];
    const float* Wf = (const float*)d_in[2];
    const float* Ws = (const float*)d_in[3];
    const float* Wo = (const float*)d_in[4];
    const int*   fi = (const int*)d_in[5];
    const int*   li = (const int*)d_in[6];
    const int*   maskI = (const int*)d_in[7];
    const unsigned char* maskB = (const unsigned char*)d_in[7];
    float* out = (float*)d_out;
    float* ws  = (float*)d_ws;

    // workspace layout (floats): total ~2.39 MB
    float* muP = ws;                          // [512][128]
    float* Uw  = ws + 512 * 128;              // [512][1024]
    float* lw  = Uw + (size_t)512 * 1024;     // [512][8]
    float* gpw = lw + 512 * 8;                // [256][128]
    float* sw  = gpw + 256 * 128;             // [512]

    k1_mean   <<<dim3(512), dim3(512),  0, stream>>>(E, muP);
    k2_attn   <<<dim3(512), dim3(512),  0, stream>>>(E, Wn, Wf, Ws, fi, li,
                                                     maskI, maskB, muP, Uw, lw);
    k3_glimpse<<<dim3(256), dim3(1024), 0, stream>>>(Wn, Wo, Uw, lw, gpw);
    k4_logits <<<dim3(512), dim3(512),  0, stream>>>(E, maskI, maskB, gpw, out, sw);
    k5_norm   <<<dim3(512), dim3(512),  0, stream>>>(sw, out);
}

// Round 13
// 335.616 us; speedup vs baseline: 1.3914x; 1.0371x over previous
//
#include <hip/hip_runtime.h>

// Problem: B=256, N=1000, D=128, H=8, dk=16.
// R11: R10 fixed the spill (k2 VGPR 108, WRITE 437MB->2MB, 467->348us) but
// k2=119us at VALU 21% / HBM 0.6TB/s = latency-bound: loads issued right
// before use, 3 barriers/tile, redundant ct round-trip (the 8-lane shfl_xor
// butterfly already gives ALL lanes all 8 reduced pch values).
// Changes vs R10 (same 5-pass skeleton):
//  k2: exp fused into compat (pt written from registers; ct + 1 barrier/tile
//      deleted -> 2 barriers/tile); tile t+1's E rows + mask PREFETCHED into
//      registers during tile t's compat, consumed 2 barriers later (L3
//      latency hidden); tile 0 prefetched at kernel entry under the prologue.
//  k4: 4 lanes/row + shfl_xor(w=4) reduce -> ZERO in-loop barriers (was 8).
//  k1/k3/k5 unchanged.

#define NEG (-1e9f)

// ---------------- K1: partial mean sums over this half's 500 rows ----------
__global__ __launch_bounds__(512, 4) void k1_mean(
    const float* __restrict__ E, float* __restrict__ muP)
{
    const int bid = blockIdx.x;
    const int b = bid & 255, half = bid >> 8;
    const int blk = b * 2 + half;
    const int t = threadIdx.x;
    const int r0g = half * 500;
    __shared__ float4 sc[512];
    const float4* E4 = (const float4*)(E + (size_t)b * 128000);
    const int cm = t & 31, sm = t >> 5;       // 16 slices x 32 cols
    float4 acc = make_float4(0.f, 0.f, 0.f, 0.f);
    for (int r = sm; r < 500; r += 16) {
        const float4 v = E4[(r0g + r) * 32 + cm];
        acc.x += v.x; acc.y += v.y; acc.z += v.z; acc.w += v.w;
    }
    sc[t] = acc;
    __syncthreads();
    if (t < 32) {
        float4 a = sc[t];
        #pragma unroll
        for (int s = 1; s < 16; ++s) {
            const float4 v = sc[s * 32 + t];
            a.x += v.x; a.y += v.y; a.z += v.z; a.w += v.w;
        }
        ((float4*)(muP + (size_t)blk * 128))[t] = a;   // partial SUM
    }
}

// ---------------- K2: q/qkp + no-max attention partials (prefetched) -------
__global__ __launch_bounds__(512, 2) void k2_attn(
    const float* __restrict__ E, const float* __restrict__ Wn,
    const float* __restrict__ Wf, const float* __restrict__ Ws,
    const int* __restrict__ fi, const int* __restrict__ li,
    const int* __restrict__ maskI, const unsigned char* __restrict__ maskB,
    const float* __restrict__ muP, float* __restrict__ Uw,
    float* __restrict__ lw)
{
    const int bid = blockIdx.x;
    const int b = bid & 255, half = bid >> 8;
    const int blk = b * 2 + half;
    const int i0 = b * 2, i1 = i0 + 1;
    const int t = threadIdx.x;
    const int r0g = half * 500;

    __shared__ float4 Et4[2048];     // 32 KB: 64-row E tile / slice reduce
    __shared__ float4 qk4[256];      // qkp, float4-slot swizzle s^(s>>2)
    __shared__ float4 pt4[128];      // p [row][h], 512 floats
    __shared__ float4 mu4[32], e14[32], e24[32];
    __shared__ float q[128];
    __shared__ float qred[4][128];
    __shared__ float redh[72];
    __shared__ int flagS;

    float* const mu  = (float*)mu4;
    float* const e1  = (float*)e14;
    float* const e2  = (float*)e24;
    float* const pt  = (float*)pt4;
    float* const qkf = (float*)qk4;
    float* const Etf = (float*)Et4;

    const float4* E4 = (const float4*)(E + (size_t)b * 128000);

    const int rr = t >> 3, qq = t & 7;     // stage: 64 rows x 8 lanes
    const int esl = t >> 7, ec = t & 127;  // accum: 4 slices x 128 cols

    // --- prefetch tile 0 (rows 0..63 always < 500) at entry: completes
    //     under the q/qkp prologue ---
    float4 v[4];
    #pragma unroll
    for (int i = 0; i < 4; ++i) v[i] = E4[(r0g + rr) * 32 + qq * 4 + i];
    int miC = maskI[b * 1000 + r0g + rr];
    unsigned char mbC = maskB[b * 1000 + r0g + rr];

    if (t == 0) flagS = 0;
    // mask-format probe: int32 upload => upper 3 bytes of every word zero.
    const uint4 dv = ((const uint4*)maskI)[t];          // first 8 KB
    const unsigned det = (dv.x | dv.y | dv.z | dv.w) & 0xFFFFFF00u;

    if (t < 128) {
        mu[t] = (muP[(size_t)i0 * 128 + t] + muP[(size_t)i1 * 128 + t])
                * (1.0f / 1000.0f);
    } else if (t < 160) {
        e14[t - 128] = E4[fi[b] * 32 + (t - 128)];
    } else if (t < 192) {
        e24[t - 160] = E4[li[b] * 32 + (t - 160)];
    }
    __syncthreads();
    if (det) atomicOr(&flagS, 1);

    // q = mu@Wf + e1@Ws[0:128] + e2@Ws[128:256], 4-way k-split
    {
        const int part = t >> 7, d = t & 127;
        float acc = 0.f;
        const int k0 = part * 96;
        for (int k = k0; k < k0 + 96; ++k) {
            const float s = (k < 128) ? mu[k] : (k < 256 ? e1[k - 128] : e2[k - 256]);
            const float w = (k < 128) ? Wf[k * 128 + d] : Ws[(k - 128) * 128 + d];
            acc += s * w;
        }
        qred[part][d] = acc;
    }
    __syncthreads();
    if (t < 128) q[t] = qred[0][t] + qred[1][t] + qred[2][t] + qred[3][t];
    __syncthreads();
    // qkp[h][c] -> qk4 (LDS only), 4 c-groups
    {
        const int j = t & 127, cg = t >> 7;
        const float qj = q[j];
        for (int c0 = 0; c0 < 128; c0 += 4) {
            const int c = c0 + cg;
            float vv = Wn[c * 384 + j] * qj;
            vv += __shfl_down(vv, 8, 16);
            vv += __shfl_down(vv, 4, 16);
            vv += __shfl_down(vv, 2, 16);
            vv += __shfl_down(vv, 1, 16);
            if ((j & 15) == 0) {
                const int h = j >> 4, s = c >> 2;
                qkf[h * 128 + (s ^ (s >> 2)) * 4 + (c & 3)] = vv * 0.25f;
            }
        }
    }
    __syncthreads();
    const bool useB = (flagS != 0);

    // --- main loop: 8 tiles x 64 rows, 2 barriers/tile, prefetch t+1 ---
    float eacc[8];
    #pragma unroll
    for (int h = 0; h < 8; ++h) eacc[h] = 0.f;
    float lacc = 0.f;

    for (int tile = 0; tile < 8; ++tile) {
        const int lr = tile * 64 + rr;
        const bool valid = (lr < 500);
        float pch[8];
        #pragma unroll
        for (int h = 0; h < 8; ++h) pch[h] = 0.f;
        #pragma unroll
        for (int i = 0; i < 4; ++i) {
            const int grp = qq * 4 + i;
            Et4[rr * 32 + grp] = v[i];        // linear row-major tile
            const int sg = grp ^ (grp >> 2);
            #pragma unroll
            for (int h = 0; h < 8; ++h) {
                const float4 w = qk4[h * 32 + sg];
                pch[h] += v[i].x * w.x + v[i].y * w.y + v[i].z * w.z + v[i].w * w.w;
            }
        }
        #pragma unroll
        for (int m = 1; m <= 4; m <<= 1) {
            #pragma unroll
            for (int h = 0; h < 8; ++h) pch[h] += __shfl_xor(pch[h], m, 8);
        }
        // fused mask+exp: every lane holds all reduced pch; write own h=qq.
        const bool msk = !valid || (useB ? (mbC != 0) : (miC != 0));
        pt[rr * 8 + qq] = msk ? 0.f : __expf(pch[qq]);

        // prefetch tile+1 into registers (consumed after 2 barriers)
        float4 vn[4];
        int miN = 1; unsigned char mbN = 1;
        #pragma unroll
        for (int i = 0; i < 4; ++i) vn[i] = make_float4(0.f, 0.f, 0.f, 0.f);
        if (tile < 7) {
            const int lr2 = lr + 64;
            if (lr2 < 500) {
                #pragma unroll
                for (int i = 0; i < 4; ++i)
                    vn[i] = E4[(r0g + lr2) * 32 + qq * 4 + i];
                miN = maskI[b * 1000 + r0g + lr2];
                mbN = maskB[b * 1000 + r0g + lr2];
            }
        }
        __syncthreads();                    // Et4 + pt ready
        // accumulate U and l partials
        #pragma unroll
        for (int j = 0; j < 16; ++j) {
            const int r = esl * 16 + j;
            const float ev = Etf[r * 128 + ec];   // stride-1: 2-way, free
            const float4 p0 = pt4[r * 2];         // broadcast
            const float4 p1 = pt4[r * 2 + 1];
            eacc[0] += p0.x * ev; eacc[1] += p0.y * ev;
            eacc[2] += p0.z * ev; eacc[3] += p0.w * ev;
            eacc[4] += p1.x * ev; eacc[5] += p1.y * ev;
            eacc[6] += p1.z * ev; eacc[7] += p1.w * ev;
        }
        if (t < 64) {
            const int h = t & 7, part = t >> 3;
            #pragma unroll
            for (int r = 0; r < 8; ++r) lacc += pt[(part * 8 + r) * 8 + h];
        }
        __syncthreads();                    // done reading before next store
        #pragma unroll
        for (int i = 0; i < 4; ++i) v[i] = vn[i];
        miC = miN; mbC = mbN;
    }

    // slice-reduce U (4 slices) and l (8 parts), publish to workspace
    #pragma unroll
    for (int h = 0; h < 8; ++h) Etf[esl * 1024 + h * 128 + ec] = eacc[h];
    if (t < 64) redh[(t >> 3) * 9 + (t & 7)] = lacc;
    __syncthreads();
    #pragma unroll
    for (int e = 0; e < 2; ++e) {
        const int idx = t + e * 512;
        Uw[(size_t)blk * 1024 + idx] =
            Etf[idx] + Etf[1024 + idx] + Etf[2048 + idx] + Etf[3072 + idx];
    }
    if (t < 8) {
        float s = 0.f;
        #pragma unroll
        for (int p = 0; p < 8; ++p) s += redh[p * 9 + t];
        lw[blk * 8 + t] = s;
    }
}

// ---------------- K3: combine halves -> Ebar -> heads -> glimpse -> gp -----
__global__ __launch_bounds__(1024) void k3_glimpse(
    const float* __restrict__ Wn, const float* __restrict__ Wo,
    const float* __restrict__ Uw, const float* __restrict__ lw,
    float* __restrict__ gpw)
{
    const int b = blockIdx.x;
    const int t = threadIdx.x;
    const int i0 = b * 2, i1 = i0 + 1;
    __shared__ float EbarF[1024];
    __shared__ float linv[8];
    __shared__ float heads[128], gl[128];
    __shared__ float qred[8][128];
    if (t < 8) linv[t] = 1.0f / (lw[i0 * 8 + t] + lw[i1 * 8 + t]);
    __syncthreads();
    EbarF[t] = (Uw[(size_t)i0 * 1024 + t] + Uw[(size_t)i1 * 1024 + t]) * linv[t >> 7];
    __syncthreads();
    {
        const int part = t >> 7, d = t & 127, h = d >> 4;
        float acc = 0.f;
        const int c0 = part * 16;
        for (int c = c0; c < c0 + 16; ++c) acc += EbarF[h * 128 + c] * Wn[c * 384 + 128 + d];
        qred[part][d] = acc;
    }
    __syncthreads();
    if (t < 128) {
        float a = 0.f;
        #pragma unroll
        for (int p = 0; p < 8; ++p) a += qred[p][t];
        heads[t] = a;
    }
    __syncthreads();
    {
        const int part = t >> 7, d = t & 127;
        float acc = 0.f;
        const int j0 = part * 16;
        for (int j = j0; j < j0 + 16; ++j) acc += heads[j] * Wo[j * 128 + d];
        qred[part][d] = acc;
    }
    __syncthreads();
    if (t < 128) {
        float a = 0.f;
        #pragma unroll
        for (int p = 0; p < 8; ++p) a += qred[p][t];
        gl[t] = a;
    }
    __syncthreads();
    {
        const int part = t >> 7, c = t & 127;
        float acc = 0.f;
        const int d0 = part * 16;
        for (int d = d0; d < d0 + 16; ++d) acc += Wn[c * 384 + 256 + d] * gl[d];
        qred[part][c] = acc;
    }
    __syncthreads();
    if (t < 128) {
        float a = 0.f;
        #pragma unroll
        for (int p = 0; p < 8; ++p) a += qred[p][t];
        gpw[(size_t)b * 128 + t] = a * 0.08838834764831845f;   // 1/sqrt(128)
    }
}

// ---------------- K4: logits, barrier-free rows (4 lanes/row + shfl) -------
__global__ __launch_bounds__(512, 2) void k4_logits(
    const float* __restrict__ E,
    const int* __restrict__ maskI, const unsigned char* __restrict__ maskB,
    const float* __restrict__ gpw, float* __restrict__ out,
    float* __restrict__ sw)
{
    const int bid = blockIdx.x;
    const int b = bid & 255, half = bid >> 8;
    const int blk = b * 2 + half;
    const int t = threadIdx.x;
    const int r0g = half * 500;
    __shared__ float4 gp4[32];
    __shared__ float redw[8];
    __shared__ int flagS;
    const float4* E4 = (const float4*)(E + (size_t)b * 128000);
    if (t == 0) flagS = 0;
    const uint4 dv = ((const uint4*)maskI)[t];
    const unsigned det = (dv.x | dv.y | dv.z | dv.w) & 0xFFFFFF00u;
    if (t < 32) gp4[t] = ((const float4*)(gpw + (size_t)b * 128))[t];
    __syncthreads();
    if (det) atomicOr(&flagS, 1);
    __syncthreads();                        // flagS final before use
    const bool useB = (flagS != 0);

    float sacc = 0.f;
    const int row = t >> 2, sub = t & 3;    // 128 rows x 4 lanes (8 f4 each)
    #pragma unroll
    for (int tile = 0; tile < 4; ++tile) {
        const int lr = tile * 128 + row;
        const int g = r0g + lr;
        float acc = 0.f;
        if (lr < 500) {
            #pragma unroll
            for (int i = 0; i < 8; ++i) {
                const float4 vv = E4[g * 32 + sub * 8 + i];
                const float4 ww = gp4[sub * 8 + i];
                acc += vv.x * ww.x + vv.y * ww.y + vv.z * ww.z + vv.w * ww.w;
            }
        }
        acc += __shfl_xor(acc, 1, 4);
        acc += __shfl_xor(acc, 2, 4);
        if (sub == 0 && lr < 500) {
            float zz = 10.0f * tanhf(acc);
            const bool m = useB ? (maskB[b * 1000 + g] != 0)
                                : (maskI[b * 1000 + g] != 0);
            if (m) zz = NEG;
            out[(size_t)b * 1000 + g] = zz;
            sacc += __expf(zz - 10.0f);     // z<=10 -> no overflow; exp(NEG)=0
        }
    }
    // block reduce (nonzero only in sub==0 lanes)
    float sv = sacc;
    #pragma unroll
    for (int off = 32; off > 0; off >>= 1) sv += __shfl_down(sv, off, 64);
    if ((t & 63) == 0) redw[t >> 6] = sv;
    __syncthreads();
    if (t == 0) {
        float s = 0.f;
        #pragma unroll
        for (int i = 0; i < 8; ++i) s += redw[i];
        sw[blk] = s;
    }
}

// ---------------- K5: out -= LSE (combine half exp-sums) -------------------
__global__ __launch_bounds__(512, 4) void k5_norm(
    const float* __restrict__ sw, float* __restrict__ out)
{
    const int bid = blockIdx.x;
    const int b = bid & 255, half = bid >> 8;
    const int t = threadIdx.x;
    const int r0g = half * 500;
    const float s = sw[b * 2] + sw[b * 2 + 1];
    const float lse = 10.0f + __logf(s);
    if (t < 500) out[(size_t)b * 1000 + r0g + t] -= lse;
}

// ---------------------------------------------------------------------------
extern "C" void kernel_launch(void* const* d_in, const int* in_sizes, int n_in,
                              void* d_out, int out_size, void* d_ws, size_t ws_size,
                              hipStream_t stream) {
    const float* E  = (const float*)d_in[0];
    const float* Wn = (const float*)d_in[1];
    const float* Wf = (const float*)d_in[2];
    const float* Ws = (const float*)d_in[3];
    const float* Wo = (const float*)d_in[4];
    const int*   fi = (const int*)d_in[5];
    const int*   li = (const int*)d_in[6];
    const int*   maskI = (const int*)d_in[7];
    const unsigned char* maskB = (const unsigned char*)d_in[7];
    float* out = (float*)d_out;
    float* ws  = (float*)d_ws;

    // workspace layout (floats): total ~2.39 MB
    float* muP = ws;                          // [512][128]
    float* Uw  = ws + 512 * 128;              // [512][1024]
    float* lw  = Uw + (size_t)512 * 1024;     // [512][8]
    float* gpw = lw + 512 * 8;                // [256][128]
    float* sw  = gpw + 256 * 128;             // [512]

    k1_mean   <<<dim3(512), dim3(512),  0, stream>>>(E, muP);
    k2_attn   <<<dim3(512), dim3(512),  0, stream>>>(E, Wn, Wf, Ws, fi, li,
                                                     maskI, maskB, muP, Uw, lw);
    k3_glimpse<<<dim3(256), dim3(1024), 0, stream>>>(Wn, Wo, Uw, lw, gpw);
    k4_logits <<<dim3(512), dim3(512),  0, stream>>>(E, maskI, maskB, gpw, out, sw);
    k5_norm   <<<dim3(512), dim3(512),  0, stream>>>(sw, out);
}